// Round 5
// baseline (291.175 us; speedup 1.0000x reference)
//
#include <hip/hip_runtime.h>
#include <hip/hip_bf16.h>
#include <math.h>

// PCNN fused: Conv1d(k=3,pad=1) -> masked piecewise max-pool -> tanh
// R13: 2 batches per accumulator set, pipelined pairs.
//  - Block = 4 batches (2 pairs), 8 waves, launch_bounds(512,2) (256-reg tier,
//    8 waves/CU). Per chunk: 4 B frags loaded ONCE, 8 A ds_reads (2 tiles),
//    32-MFMA cluster -> B L2 traffic halved per batch, 2x latency cover.
//  - Pair p+1 X tiles staged DURING pair p's K-loop: one R12 stage-iter per
//    chunk (load@kk, cvt+write@kk+3, 3-slot reg ring = 24 transient VGPR).
//  - LDS = 4 tiles + 4 sel = 163008 B (1 block/CU); grid 512 = 2 seq blocks/CU.
//  - Barriers only at pair boundaries (3 per pair) - no per-chunk rendezvous.
//  - Tile layout / halo remap / frag math / epilogue identical to R12.

#define B_SZ   2048
#define L_SEQ  128
#define C_INCH 150
#define H_OUT  230
#define RS     152      // row stride in bf16 (304 B); 152 = 19*8
#define NROW   129      // rows l=-1..127; l=128 halo remapped to row 0 (both zero)
#define NS8    2451     // short8s per tile = NROW*RS/8
#define TILE   (NROW * RS)   // 19608 shorts = 39216 B
#define IB     4        // batches per block (2 pairs)

typedef __attribute__((ext_vector_type(8))) short short8;   // 8 bf16
typedef __attribute__((ext_vector_type(4))) float float4v;  // mfma acc

static __device__ __forceinline__ unsigned short f2bf(float f) {
    union { float f; unsigned u; } x{f};
    unsigned r = (x.u + 0x7FFFu + ((x.u >> 16) & 1u)) >> 16;  // RNE
    return (unsigned short)r;
}

static __device__ __forceinline__ unsigned cvt2(float2 f) {
    __hip_bfloat162 h = __float22bfloat162_rn(f);   // v_cvt_pk_bf16_f32
    union { __hip_bfloat162 h; unsigned u; } c{h};
    return c.u;
}

static __device__ __forceinline__ float tanh_fast_pos(float v) {
    float e = __expf(2.0f * v);
    return 1.0f - 2.0f / (e + 1.0f);
}

// One staging iteration, split T14-style (verified R11/R12 math):
// t = it*512+tid indexes short8s; row = t/19 (l = row-1), j = t%19.
static __device__ __forceinline__ void stage_load(const float* __restrict__ xb,
                                                  int tid, int it, float2 pl[4]) {
    const int t   = it * 512 + tid;
    const int tc  = (t < NS8) ? t : (NS8 - 1);
    const int row = tc / 19;
    const int j   = tc - row * 19;
    const int rm1 = (row > 0) ? (row - 1) : 0;
    const float* s = xb + rm1 * C_INCH + j * 8;
    pl[0] = *(const float2*)(s);
    pl[1] = *(const float2*)(s + 2);
    pl[2] = *(const float2*)(s + 4);
    pl[3] = *(const float2*)(s + ((j < 18) ? 6 : 4));   // j=18 dup, zeroed later
}

static __device__ __forceinline__ void stage_write(unsigned short* __restrict__ dst,
                                                   int tid, int it, const float2 pl[4]) {
    const int t   = it * 512 + tid;
    const int tc  = (t < NS8) ? t : (NS8 - 1);
    const int row = tc / 19;
    const int j   = tc - row * 19;
    uint4 u;
    u.x = cvt2(pl[0]); u.y = cvt2(pl[1]); u.z = cvt2(pl[2]); u.w = cvt2(pl[3]);
    const bool z = (row == 0);                 // halo row -> zeros
    u.x = z ? 0u : u.x;
    u.y = z ? 0u : u.y;
    u.z = z ? 0u : u.z;
    u.w = (z || j == 18) ? 0u : u.w;           // pad cols 150,151 -> zero
    if (t < NS8) *(uint4*)(dst + (size_t)t * 8) = u;
}

// Epilogue part 1 (per batch): selector-add masked max + shfl reduce -> sP.
// C/D layout: col(h)=c15, row(l in frag)=q*4+r  (verified R4-R12).
static __device__ __forceinline__ void epi_partial(const float4v acc[4][4],
                                                   const float* __restrict__ sel,
                                                   float* __restrict__ sP,
                                                   int mh, int nh, int q, int c15) {
    float pz[4][3];
    #pragma unroll
    for (int nj = 0; nj < 4; ++nj)
        #pragma unroll
        for (int p = 0; p < 3; ++p) pz[nj][p] = -1e30f;

    #pragma unroll
    for (int mi = 0; mi < 4; ++mi) {
        const int l0 = mh * 64 + mi * 16 + q * 4;            // mult of 4
        const float4v* sp = (const float4v*)(sel + l0 * 3);  // 48B, 16B-aligned
        const float4v s0 = sp[0], s1 = sp[1], s2 = sp[2];
        const float sl[12] = {s0.x, s0.y, s0.z, s0.w, s1.x, s1.y,
                              s1.z, s1.w, s2.x, s2.y, s2.z, s2.w};
        #pragma unroll
        for (int nj = 0; nj < 4; ++nj)
            #pragma unroll
            for (int r = 0; r < 4; ++r) {
                const float y = acc[mi][nj][r];
                pz[nj][0] = fmaxf(pz[nj][0], y + sl[r * 3 + 0]);
                pz[nj][1] = fmaxf(pz[nj][1], y + sl[r * 3 + 1]);
                pz[nj][2] = fmaxf(pz[nj][2], y + sl[r * 3 + 2]);
            }
    }
    #pragma unroll
    for (int nj = 0; nj < 4; ++nj) {
        float p0 = pz[nj][0], p1 = pz[nj][1], p2 = pz[nj][2];
        p0 = fmaxf(p0, __shfl_xor(p0, 16, 64));
        p1 = fmaxf(p1, __shfl_xor(p1, 16, 64));
        p2 = fmaxf(p2, __shfl_xor(p2, 16, 64));
        p0 = fmaxf(p0, __shfl_xor(p0, 32, 64));
        p1 = fmaxf(p1, __shfl_xor(p1, 32, 64));
        p2 = fmaxf(p2, __shfl_xor(p2, 32, 64));
        if (q == 0) {
            const int hl = nh * 64 + nj * 16 + c15;          // 0..255
            float* d = sP + (mh * 256 + hl) * 3;
            d[0] = p0; d[1] = p1; d[2] = p2;
        }
    }
}

// Epilogue part 2 (per batch): combine m-halves, bias, relu-clamp, tanh, store.
static __device__ __forceinline__ void epi_store(float* __restrict__ outb,
                                                 const float* __restrict__ sP,
                                                 const float* __restrict__ bias,
                                                 int tid) {
    for (int t = tid; t < 768; t += 512) {
        const int h = t / 3;
        const int p = t - h * 3;
        if (h < H_OUT) {
            float v = fmaxf(sP[h * 3 + p], sP[(256 + h) * 3 + p]);
            v = fmaxf(0.0f, v + bias[h]);
            outb[h * 3 + p] = tanh_fast_pos(v);
        }
    }
}

// Pack W[h][c][k] fp32 -> Wpk fragment order (verified R4-R12):
//   kk = k*5+kc, ht = h/16, lane = q*16+c15
//   Wpk[((kk*16+ht)*64+lane)*8 + e] = bf16(W[ht*16+c15][kc*32+q*8+e][k])
__global__ void pack_w_kernel(const float* __restrict__ W,
                              unsigned short* __restrict__ Wpk) {
    int t = blockIdx.x * 256 + threadIdx.x;       // < 15360
    int kk   = t >> 10;
    int rem  = t & 1023;
    int ht   = rem >> 6;
    int lane = rem & 63;
    int q    = lane >> 4;
    int c15  = lane & 15;
    int k    = kk / 5;
    int kc   = kk - k * 5;
    int h    = ht * 16 + c15;
    int cb   = kc * 32 + q * 8;
    unsigned short v[8];
    #pragma unroll
    for (int e = 0; e < 8; ++e) {
        int c = cb + e;
        float f = (h < H_OUT && c < C_INCH) ? W[h * 450 + c * 3 + k] : 0.0f;
        v[e] = f2bf(f);
    }
    *(short8*)(Wpk + (size_t)t * 8) = *(short8*)v;
}

__global__ void __launch_bounds__(512, 2)
pcnn_mfma(const float* __restrict__ Xea, const int* __restrict__ Xmask,
          const unsigned short* __restrict__ Wpk,
          const float* __restrict__ bias, float* __restrict__ out) {
    __shared__ __align__(16) unsigned short sX[4][TILE];     // 156864 B
    __shared__ __align__(16) float sSel[4][L_SEQ * 3];       // 6144 B (163008)

    const int tid  = threadIdx.x;
    const int wv   = tid >> 6;        // 0..7
    const int lane = tid & 63;
    const int q    = lane >> 4;
    const int c15  = lane & 15;
    const int mh   = wv & 1;          // m-half: l offset 64*mh
    const int nh   = wv >> 1;         // n-quarter: h offset 64*nh (0..3)
    const int b0   = blockIdx.x * IB;

    const unsigned short* wp = Wpk + ((size_t)(nh * 4) * 64 + lane) * 8;

    // B chunk 0 preload
    short8 bb[2][4];
    #pragma unroll
    for (int nj = 0; nj < 4; ++nj)
        bb[0][nj] = *(const short8*)(wp + nj * 512);

    // ---- prologue: stage tiles 0,1 (batches b0, b0+1), deep issue ----
    {
        const float* xb0 = Xea + (size_t)b0 * (L_SEQ * C_INCH);
        float2 pA[5][4];
        #pragma unroll
        for (int it = 0; it < 5; ++it) stage_load(xb0, tid, it, pA[it]);
        if (tid < L_SEQ) {
            const int m0 = Xmask[(size_t)b0 * L_SEQ + tid];
            const int m1 = Xmask[(size_t)(b0 + 1) * L_SEQ + tid];
            sSel[0][tid * 3 + 0] = (m0 == 1) ? 0.0f : -1e30f;
            sSel[0][tid * 3 + 1] = (m0 == 2) ? 0.0f : -1e30f;
            sSel[0][tid * 3 + 2] = (m0 == 3) ? 0.0f : -1e30f;
            sSel[1][tid * 3 + 0] = (m1 == 1) ? 0.0f : -1e30f;
            sSel[1][tid * 3 + 1] = (m1 == 2) ? 0.0f : -1e30f;
            sSel[1][tid * 3 + 2] = (m1 == 3) ? 0.0f : -1e30f;
        }
        #pragma unroll
        for (int it = 0; it < 5; ++it) stage_write(sX[0], tid, it, pA[it]);
        const float* xb1 = xb0 + L_SEQ * C_INCH;
        float2 pB[5][4];
        #pragma unroll
        for (int it = 0; it < 5; ++it) stage_load(xb1, tid, it, pB[it]);
        #pragma unroll
        for (int it = 0; it < 5; ++it) stage_write(sX[1], tid, it, pB[it]);
    }
    __syncthreads();

    float2 stg[3][4];      // staging ring (pair-1 prefetch), static-indexed
    int mvA = 0, mvB = 0;

    #pragma unroll
    for (int pr = 0; pr < 2; ++pr) {
        const int bA = b0 + 2 * pr;

        float4v accA[4][4], accB[4][4];
        #pragma unroll
        for (int mi = 0; mi < 4; ++mi)
            #pragma unroll
            for (int nj = 0; nj < 4; ++nj) {
                accA[mi][nj] = (float4v){0.f, 0.f, 0.f, 0.f};
                accB[mi][nj] = (float4v){0.f, 0.f, 0.f, 0.f};
            }

        const unsigned short* a0pA = sX[2 * pr]     + (mh * 64 + c15) * RS + q * 8;
        const unsigned short* a0pB = sX[2 * pr + 1] + (mh * 64 + c15) * RS + q * 8;
        // l=128 halo hits only at (mh=1,mi=3,c15=15,k=2); remap to row 0 (zeros)
        const unsigned short* a3pA = (mh == 1 && c15 == 15) ? (a0pA - 129 * RS) : a0pA;
        const unsigned short* a3pB = (mh == 1 && c15 == 15) ? (a0pB - 129 * RS) : a0pB;

        #pragma unroll
        for (int kk = 0; kk < 15; ++kk) {
            const int g   = pr * 15 + kk;
            const int cur = g & 1;
            // B prefetch for next global chunk (shared by both batches)
            if (g < 29) {
                const int kn = (g + 1) % 15;
                #pragma unroll
                for (int nj = 0; nj < 4; ++nj)
                    bb[cur ^ 1][nj] =
                        *(const short8*)(wp + (size_t)kn * 8192 + nj * 512);
            }
            // A reads: both tiles of the pair
            const int k  = kk / 5;
            const int kc = kk - k * 5;
            short8 aA[4], aB[4];
            #pragma unroll
            for (int mi = 0; mi < 4; ++mi) {
                const unsigned short* pA_ = (mi == 3 && k == 2) ? a3pA : a0pA;
                const unsigned short* pB_ = (mi == 3 && k == 2) ? a3pB : a0pB;
                aA[mi] = *(const short8*)(pA_ + (mi * 16 + k) * RS + kc * 32);
                aB[mi] = *(const short8*)(pB_ + (mi * 16 + k) * RS + kc * 32);
            }
            // next-pair staging: loads (s = kk-1, 0..9), one iter per chunk
            if (pr == 0 && kk >= 1 && kk <= 10) {
                const int s = kk - 1;
                const float* xs =
                    Xea + (size_t)(b0 + 2 + (s >= 5 ? 1 : 0)) * (L_SEQ * C_INCH);
                stage_load(xs, tid, s % 5, stg[s % 3]);
            }
            if (pr == 0 && kk == 13 && tid < L_SEQ) {
                mvA = Xmask[(size_t)(b0 + 2) * L_SEQ + tid];
                mvB = Xmask[(size_t)(b0 + 3) * L_SEQ + tid];
            }
            // 32-MFMA cluster: both batches share bb[cur]
            __builtin_amdgcn_s_setprio(1);
            #pragma unroll
            for (int mi = 0; mi < 4; ++mi)
                #pragma unroll
                for (int nj = 0; nj < 4; ++nj)
                    accA[mi][nj] = __builtin_amdgcn_mfma_f32_16x16x32_bf16(
                        aA[mi], bb[cur][nj], accA[mi][nj], 0, 0, 0);
            #pragma unroll
            for (int mi = 0; mi < 4; ++mi)
                #pragma unroll
                for (int nj = 0; nj < 4; ++nj)
                    accB[mi][nj] = __builtin_amdgcn_mfma_f32_16x16x32_bf16(
                        aB[mi], bb[cur][nj], accB[mi][nj], 0, 0, 0);
            __builtin_amdgcn_s_setprio(0);
            // next-pair staging: cvt+write (s = kk-3, 0..9), 2 chunks behind
            if (pr == 0 && kk >= 3 && kk <= 12) {
                const int s = kk - 3;
                stage_write(sX[2 + (s >= 5 ? 1 : 0)], tid, s % 5, stg[s % 3]);
            }
            if (pr == 0 && kk == 14 && tid < L_SEQ) {
                sSel[2][tid * 3 + 0] = (mvA == 1) ? 0.0f : -1e30f;
                sSel[2][tid * 3 + 1] = (mvA == 2) ? 0.0f : -1e30f;
                sSel[2][tid * 3 + 2] = (mvA == 3) ? 0.0f : -1e30f;
                sSel[3][tid * 3 + 0] = (mvB == 1) ? 0.0f : -1e30f;
                sSel[3][tid * 3 + 1] = (mvB == 2) ? 0.0f : -1e30f;
                sSel[3][tid * 3 + 2] = (mvB == 3) ? 0.0f : -1e30f;
            }
            __builtin_amdgcn_sched_barrier(0);
        }

        __syncthreads();   // all A-reads of this pair's tiles done
        // alias partials onto this pair's (dead) tiles
        epi_partial(accA, sSel[2 * pr],     (float*)sX[2 * pr],     mh, nh, q, c15);
        epi_partial(accB, sSel[2 * pr + 1], (float*)sX[2 * pr + 1], mh, nh, q, c15);
        __syncthreads();
        epi_store(out + (size_t)bA * (3 * H_OUT),
                  (const float*)sX[2 * pr], bias, tid);
        epi_store(out + (size_t)(bA + 1) * (3 * H_OUT),
                  (const float*)sX[2 * pr + 1], bias, tid);
    }
}

extern "C" void kernel_launch(void* const* d_in, const int* in_sizes, int n_in,
                              void* d_out, int out_size, void* d_ws, size_t ws_size,
                              hipStream_t stream) {
    const float* Xea   = (const float*)d_in[0];   // [2048,128,150] f32
    const int*   Xmask = (const int*)d_in[1];     // [2048,128] i32
    const float* W     = (const float*)d_in[2];   // [230,150,3] f32
    const float* bias  = (const float*)d_in[3];   // [230] f32
    float* out = (float*)d_out;                   // [2048,690] f32
    unsigned short* Wpk = (unsigned short*)d_ws;  // 245760 B

    pack_w_kernel<<<60, 256, 0, stream>>>(W, Wpk);
    pcnn_mfma<<<B_SZ / IB, 512, 0, stream>>>(Xea, Xmask, Wpk, bias, out);
}

// Round 6
// 263.633 us; speedup vs baseline: 1.1045x; 1.1045x over previous
//
#include <hip/hip_runtime.h>
#include <hip/hip_bf16.h>
#include <math.h>

// PCNN fused: Conv1d(k=3,pad=1) -> masked piecewise max-pool -> tanh
// R14: R12 with the K-loop scheduler UNPINNED.
//  - sched_barrier(0) -> sched_barrier(0x106): VALU|SALU|DS_READ may cross
//    iteration boundaries (A ds_reads software-pipeline behind the MFMA
//    cluster, killing the per-chunk exposed lgkm wait — m141's lesson in
//    reverse); VMEM stays pinned (B-load hoisting bounded, no reg blowup).
//  - s_setprio removed (m190: hurts phase-locked GEMM structures).
//  - Everything else byte-identical to verified R12 (96.7 us): barrier-free
//    K-loop, register-B double set bb[kk&1], branch-free staging,
//    tile RS=152/NROW=129, halo remap, epilogue.
//  - launch_bounds(512,4) caps total regs at 128 -> scheduler freedom
//    cannot spill (R13's failure mode fenced off).

#define B_SZ   2048
#define L_SEQ  128
#define C_INCH 150
#define H_OUT  230
#define RS     152      // row stride in bf16 (304 B); 152 = 19*8
#define NROW   129      // rows l=-1..127; l=128 halo remapped to row 0 (both zero)
#define NS8    2451     // short8s per tile = NROW*RS/8

typedef __attribute__((ext_vector_type(8))) short short8;   // 8 bf16
typedef __attribute__((ext_vector_type(4))) float float4v;  // mfma acc

static __device__ __forceinline__ unsigned short f2bf(float f) {
    union { float f; unsigned u; } x{f};
    unsigned r = (x.u + 0x7FFFu + ((x.u >> 16) & 1u)) >> 16;  // RNE
    return (unsigned short)r;
}

static __device__ __forceinline__ unsigned cvt2(float2 f) {
    __hip_bfloat162 h = __float22bfloat162_rn(f);   // v_cvt_pk_bf16_f32
    union { __hip_bfloat162 h; unsigned u; } c{h};
    return c.u;
}

static __device__ __forceinline__ float tanh_fast_pos(float v) {
    float e = __expf(2.0f * v);
    return 1.0f - 2.0f / (e + 1.0f);
}

// Pack W[h][c][k] fp32 -> Wpk fragment order (verified R4-R12):
//   kk = k*5+kc, ht = h/16, lane = q*16+c15
//   Wpk[((kk*16+ht)*64+lane)*8 + e] = bf16(W[ht*16+c15][kc*32+q*8+e][k])
__global__ void pack_w_kernel(const float* __restrict__ W,
                              unsigned short* __restrict__ Wpk) {
    int t = blockIdx.x * 256 + threadIdx.x;       // < 15360
    int kk   = t >> 10;
    int rem  = t & 1023;
    int ht   = rem >> 6;
    int lane = rem & 63;
    int q    = lane >> 4;
    int c15  = lane & 15;
    int k    = kk / 5;
    int kc   = kk - k * 5;
    int h    = ht * 16 + c15;
    int cb   = kc * 32 + q * 8;
    unsigned short v[8];
    #pragma unroll
    for (int e = 0; e < 8; ++e) {
        int c = cb + e;
        float f = (h < H_OUT && c < C_INCH) ? W[h * 450 + c * 3 + k] : 0.0f;
        v[e] = f2bf(f);
    }
    *(short8*)(Wpk + (size_t)t * 8) = *(short8*)v;
}

__global__ void __launch_bounds__(512, 4)
pcnn_mfma(const float* __restrict__ Xea, const int* __restrict__ Xmask,
          const unsigned short* __restrict__ Wpk,
          const float* __restrict__ bias, float* __restrict__ out) {
    __shared__ __align__(16) unsigned short sX[NROW * RS];   // 39216 B
    __shared__ __align__(16) float sSel[L_SEQ * 3];          // 1536 B (tot 40752)

    const int b    = blockIdx.x;
    const int tid  = threadIdx.x;
    const int wv   = tid >> 6;        // 0..7
    const int lane = tid & 63;
    const int q    = lane >> 4;
    const int c15  = lane & 15;
    const int mh   = wv & 1;          // m-half: l offset 64*mh
    const int nh   = wv >> 1;         // n-quarter: h offset 64*nh (0..3)

    const unsigned short* wp = Wpk + ((size_t)(nh * 4) * 64 + lane) * 8;

    // ---- preload B chunk 0 into set 0 (deep issue, before X staging) ----
    short8 bb[2][4];
    #pragma unroll
    for (int nj = 0; nj < 4; ++nj)
        bb[0][nj] = *(const short8*)(wp + nj * 512);

    // ---- X staging: branch-free deep issue (verified R11/R12) ----
    // t indexes short8s: row = t/19 (l = row-1), j = t%19 covers cols 8j..8j+7.
    // row 0 = zero halo. Cols 150,151 zero. Loads unconditional (clamped);
    // halo/pad handled by zero-selects; only the LDS store is guarded.
    const float* xb = Xea + (size_t)b * (L_SEQ * C_INCH);
    float2 pl[5][4];
    #pragma unroll
    for (int it = 0; it < 5; ++it) {
        const int t   = it * 512 + tid;
        const int tc  = (t < NS8) ? t : (NS8 - 1);
        const int row = tc / 19;
        const int j   = tc - row * 19;
        const int rm1 = (row > 0) ? (row - 1) : 0;
        const float* s = xb + rm1 * C_INCH + j * 8;
        pl[it][0] = *(const float2*)(s);
        pl[it][1] = *(const float2*)(s + 2);
        pl[it][2] = *(const float2*)(s + 4);
        // j=18: cols 150,151 don't exist; load dup of 148,149 (in-bounds),
        // zeroed below.
        pl[it][3] = *(const float2*)(s + ((j < 18) ? 6 : 4));
    }

    // mask -> piece selectors {0, -1e30}
    if (tid < L_SEQ) {
        int mv = Xmask[(size_t)b * L_SEQ + tid];
        sSel[tid * 3 + 0] = (mv == 1) ? 0.0f : -1e30f;
        sSel[tid * 3 + 1] = (mv == 2) ? 0.0f : -1e30f;
        sSel[tid * 3 + 2] = (mv == 3) ? 0.0f : -1e30f;
    }

    #pragma unroll
    for (int it = 0; it < 5; ++it) {
        const int t   = it * 512 + tid;
        const int tc  = (t < NS8) ? t : (NS8 - 1);
        const int row = tc / 19;
        const int j   = tc - row * 19;
        uint4 u;
        u.x = cvt2(pl[it][0]);
        u.y = cvt2(pl[it][1]);
        u.z = cvt2(pl[it][2]);
        u.w = cvt2(pl[it][3]);
        const bool z = (row == 0);             // halo row -> zeros
        u.x = z ? 0u : u.x;
        u.y = z ? 0u : u.y;
        u.z = z ? 0u : u.z;
        u.w = (z || j == 18) ? 0u : u.w;       // pad cols 150,151 -> zero
        if (t < NS8) *(uint4*)(sX + (size_t)t * 8) = u;
    }

    __syncthreads();   // X tile ready; only barrier before the epilogue

    // ---- MFMA: 15 K-chunks of 32; B in registers, alternating sets ----
    float4v acc[4][4];
    #pragma unroll
    for (int mi = 0; mi < 4; ++mi)
        #pragma unroll
        for (int nj = 0; nj < 4; ++nj)
            acc[mi][nj] = (float4v){0.f, 0.f, 0.f, 0.f};

    const unsigned short* a0p = sX + (mh * 64 + c15) * RS + q * 8;
    // l=128 halo: row mh*64+c15+mi*16+k == 129 only at (mh=1,mi=3,c15=15,k=2);
    // remap to row 0 (zeros).
    const unsigned short* a3p2 = (mh == 1 && c15 == 15) ? (a0p - 129 * RS) : a0p;

    #pragma unroll
    for (int kk = 0; kk < 15; ++kk) {
        const int cur = kk & 1;
        // issue next chunk's B loads (consumed after this chunk's MFMAs;
        // compiler's vmcnt wait lands behind the 16-MFMA cluster)
        if (kk < 14) {
            #pragma unroll
            for (int nj = 0; nj < 4; ++nj)
                bb[cur ^ 1][nj] =
                    *(const short8*)(wp + (size_t)(kk + 1) * 8192 + nj * 512);
        }
        const int k  = kk / 5;
        const int kc = kk - k * 5;
        short8 a[4];
        #pragma unroll
        for (int mi = 0; mi < 4; ++mi) {
            const unsigned short* base = (mi == 3 && k == 2) ? a3p2 : a0p;
            a[mi] = *(const short8*)(base + (mi * 16 + k) * RS + kc * 32);
        }
        #pragma unroll
        for (int mi = 0; mi < 4; ++mi)
            #pragma unroll
            for (int nj = 0; nj < 4; ++nj)
                acc[mi][nj] = __builtin_amdgcn_mfma_f32_16x16x32_bf16(
                    a[mi], bb[cur][nj], acc[mi][nj], 0, 0, 0);
        // Partial pin: VMEM and MFMA may not cross iterations (bounds B-load
        // hoisting -> no reg blowup), but VALU|SALU|DS_READ may (next chunk's
        // A ds_reads schedule behind this chunk's MFMA cluster, hiding lgkm).
        __builtin_amdgcn_sched_barrier(0x106);
    }

    // ---- Epilogue: selector-add masked max (bias deferred) ----
    // C/D layout: col(h)=c15, row(l in frag)=q*4+r
    float pz[4][3];
    #pragma unroll
    for (int nj = 0; nj < 4; ++nj)
        #pragma unroll
        for (int p = 0; p < 3; ++p) pz[nj][p] = -1e30f;

    #pragma unroll
    for (int mi = 0; mi < 4; ++mi) {
        const int l0 = mh * 64 + mi * 16 + q * 4;            // mult of 4
        const float4v* sp = (const float4v*)(sSel + l0 * 3); // 48B, 16B-aligned
        const float4v s0 = sp[0], s1 = sp[1], s2 = sp[2];
        const float sl[12] = {s0.x, s0.y, s0.z, s0.w, s1.x, s1.y,
                              s1.z, s1.w, s2.x, s2.y, s2.z, s2.w};
        #pragma unroll
        for (int nj = 0; nj < 4; ++nj)
            #pragma unroll
            for (int r = 0; r < 4; ++r) {
                const float y = acc[mi][nj][r];
                pz[nj][0] = fmaxf(pz[nj][0], y + sl[r * 3 + 0]);
                pz[nj][1] = fmaxf(pz[nj][1], y + sl[r * 3 + 1]);
                pz[nj][2] = fmaxf(pz[nj][2], y + sl[r * 3 + 2]);
            }
    }

    __syncthreads();   // all sX reads done -> alias partials onto sX
    float* sP = (float*)sX;   // [mh][h 0..255][3] = 1536 floats

    #pragma unroll
    for (int nj = 0; nj < 4; ++nj) {
        float p0 = pz[nj][0], p1 = pz[nj][1], p2 = pz[nj][2];
        p0 = fmaxf(p0, __shfl_xor(p0, 16, 64));
        p1 = fmaxf(p1, __shfl_xor(p1, 16, 64));
        p2 = fmaxf(p2, __shfl_xor(p2, 16, 64));
        p0 = fmaxf(p0, __shfl_xor(p0, 32, 64));
        p1 = fmaxf(p1, __shfl_xor(p1, 32, 64));
        p2 = fmaxf(p2, __shfl_xor(p2, 32, 64));
        if (q == 0) {
            const int hl = nh * 64 + nj * 16 + c15;          // 0..255
            float* d = sP + (mh * 256 + hl) * 3;
            d[0] = p0; d[1] = p1; d[2] = p2;
        }
    }
    __syncthreads();

    // Combine m-halves, add bias, clamp 0, tanh, store
    for (int t = tid; t < 768; t += 512) {
        const int h = t / 3;
        const int p = t - h * 3;
        if (h < H_OUT) {
            float v = fmaxf(sP[h * 3 + p], sP[(256 + h) * 3 + p]);
            v = fmaxf(0.0f, v + bias[h]);
            out[(size_t)b * (3 * H_OUT) + h * 3 + p] = tanh_fast_pos(v);
        }
    }
}

extern "C" void kernel_launch(void* const* d_in, const int* in_sizes, int n_in,
                              void* d_out, int out_size, void* d_ws, size_t ws_size,
                              hipStream_t stream) {
    const float* Xea   = (const float*)d_in[0];   // [2048,128,150] f32
    const int*   Xmask = (const int*)d_in[1];     // [2048,128] i32
    const float* W     = (const float*)d_in[2];   // [230,150,3] f32
    const float* bias  = (const float*)d_in[3];   // [230] f32
    float* out = (float*)d_out;                   // [2048,690] f32
    unsigned short* Wpk = (unsigned short*)d_ws;  // 245760 B

    pack_w_kernel<<<60, 256, 0, stream>>>(W, Wpk);
    pcnn_mfma<<<B_SZ, 512, 0, stream>>>(Xea, Xmask, Wpk, bias, out);
}